// Round 10
// baseline (916.939 us; speedup 1.0000x reference)
//
#include <hip/hip_runtime.h>
#include <hip/hip_bf16.h>

// RGCN gather-mm, etype-sorted edges.
// out[v][n] = sum_{e: dst[e]=v} sum_k feat[src[e]][k] * W[etype[e]][k][n]
//
// R10: dense projection (proj[r] = feat @ W[r], NT stores) + BUCKET sort
// (dst>>7, LDS-binned scatter -> coalesced item bursts; R9's exact-dst
// scatter burned 110us on 64B-per-4B write amplification) + per-bucket LDS
// fp32 accumulation reduce (gathers full 128B proj rows, no amplification).
// Fallback (ws too small / size guards): R4 atomic kernel.

#define NTHREADS 256
#define TM 64

typedef __attribute__((ext_vector_type(8))) __bf16 bf16x8;
typedef __attribute__((ext_vector_type(4))) float f32x4;

// ---- cvt: feat fp32 -> bf16 ----
__global__ void cvt_feat_kernel(const float* __restrict__ f,
                                __bf16* __restrict__ o, int n) {
    int i = (blockIdx.x * 256 + threadIdx.x) * 8;
    if (i >= n) return;
    float4 a = *(const float4*)(f + i);
    float4 b = *(const float4*)(f + i + 4);
    bf16x8 v;
    v[0] = (__bf16)a.x; v[1] = (__bf16)a.y; v[2] = (__bf16)a.z; v[3] = (__bf16)a.w;
    v[4] = (__bf16)b.x; v[5] = (__bf16)b.y; v[6] = (__bf16)b.z; v[7] = (__bf16)b.w;
    *(bf16x8*)(o + i) = v;
}

// ---- cvt: W [R][128][64] fp32 -> Wt [R][64][128] bf16 (transposed) ----
__global__ void cvt_w_kernel(const float* __restrict__ w,
                             __bf16* __restrict__ o, int total) {
    int idx = blockIdx.x * 256 + threadIdx.x;
    if (idx >= total) return;
    int r = idx >> 13;
    int rem = idx & 8191;
    int k = rem >> 6;
    int n = rem & 63;
    o[(r << 13) + (n << 7) + k] = (__bf16)w[idx];
}

// ---- dense projection: proj[r][node][c'] = (feat @ W[r]) permuted, NT ----
__global__ __launch_bounds__(NTHREADS)
void proj_kernel(const __bf16* __restrict__ featb, const __bf16* __restrict__ wtb,
                 int N, __bf16* __restrict__ projb) {
    __shared__ __bf16 Wt[64 * 136];

    int r = blockIdx.y;
    int t = threadIdx.x;
    const __bf16* wg = wtb + (r << 13);
    #pragma unroll
    for (int c = t; c < 1024; c += NTHREADS) {
        int n = c >> 4, kc = c & 15;
        *(bf16x8*)(&Wt[n * 136 + kc * 8]) = *(const bf16x8*)(wg + n * 128 + kc * 8);
    }
    __syncthreads();

    int wave = t >> 6, lane = t & 63;
    int q = lane >> 4, m = lane & 15;
    long node0 = (long)blockIdx.x * 128 + wave * 32;

    bf16x8 a[2][4];
    #pragma unroll
    for (int mt = 0; mt < 2; mt++) {
        long nd = node0 + mt * 16 + m;
        if (nd > N - 1) nd = N - 1;
        const __bf16* arow = featb + nd * 128;
        #pragma unroll
        for (int ks = 0; ks < 4; ks++)
            a[mt][ks] = *(const bf16x8*)(arow + ks * 32 + q * 8);
    }

    f32x4 acc[2][4] = {};
    #pragma unroll
    for (int ks = 0; ks < 4; ks++) {
        bf16x8 b0 = *(const bf16x8*)(&Wt[(0 * 16 + m) * 136 + ks * 32 + q * 8]);
        bf16x8 b1 = *(const bf16x8*)(&Wt[(1 * 16 + m) * 136 + ks * 32 + q * 8]);
        bf16x8 b2 = *(const bf16x8*)(&Wt[(2 * 16 + m) * 136 + ks * 32 + q * 8]);
        bf16x8 b3 = *(const bf16x8*)(&Wt[(3 * 16 + m) * 136 + ks * 32 + q * 8]);
        #pragma unroll
        for (int mt = 0; mt < 2; mt++) {
            acc[mt][0] = __builtin_amdgcn_mfma_f32_16x16x32_bf16(a[mt][ks], b0, acc[mt][0], 0, 0, 0);
            acc[mt][1] = __builtin_amdgcn_mfma_f32_16x16x32_bf16(a[mt][ks], b1, acc[mt][1], 0, 0, 0);
            acc[mt][2] = __builtin_amdgcn_mfma_f32_16x16x32_bf16(a[mt][ks], b2, acc[mt][2], 0, 0, 0);
            acc[mt][3] = __builtin_amdgcn_mfma_f32_16x16x32_bf16(a[mt][ks], b3, acc[mt][3], 0, 0, 0);
        }
    }

    // C/D: col = nt*16+m, node = mt*16+q*4+reg. Permuted c' = m*4+nt.
    // NT stores: keep featb resident in L3 (R9 FETCH 201MB = write-evict).
    #pragma unroll
    for (int mt = 0; mt < 2; mt++) {
        #pragma unroll
        for (int reg = 0; reg < 4; reg++) {
            long nd = node0 + mt * 16 + q * 4 + reg;
            if (nd < N) {
                union { unsigned long long u; __bf16 h[4]; } pk;
                pk.h[0] = (__bf16)acc[mt][0][reg];
                pk.h[1] = (__bf16)acc[mt][1][reg];
                pk.h[2] = (__bf16)acc[mt][2][reg];
                pk.h[3] = (__bf16)acc[mt][3][reg];
                __builtin_nontemporal_store(pk.u,
                    (unsigned long long*)(projb + ((size_t)r * N + nd) * 64 + m * 4));
            }
        }
    }
}

// ---- bucket histogram (bucket = dst>>7) ----
__global__ __launch_bounds__(1024)
void bucket_hist(const int* __restrict__ dst, int E, int* __restrict__ bhist) {
    __shared__ int lh[1024];
    int t = threadIdx.x;
    lh[t] = 0;
    __syncthreads();
    long base = (long)blockIdx.x * 8192;
    #pragma unroll
    for (int i = 0; i < 8; i++) {
        long e = base + t + 1024 * i;
        if (e < E) atomicAdd(&lh[dst[e] >> 7], 1);
    }
    __syncthreads();
    if (lh[t]) atomicAdd(&bhist[t], lh[t]);   // lh[t]==0 for t>=NB
}

// ---- scan buckets (NB <= 1024) -> boff (exclusive) + bcur copy ----
__global__ __launch_bounds__(1024)
void bucket_scan(const int* __restrict__ bhist, int NB, int E,
                 int* __restrict__ boff, int* __restrict__ bcur) {
    __shared__ int sm[1024];
    int t = threadIdx.x;
    int v = (t < NB) ? bhist[t] : 0;
    sm[t] = v;
    __syncthreads();
    for (int s = 1; s < 1024; s <<= 1) {
        int add = (t >= s) ? sm[t - s] : 0;
        __syncthreads();
        sm[t] += add;
        __syncthreads();
    }
    if (t < NB) { int ex = sm[t] - v; boff[t] = ex; bcur[t] = ex; }
    if (t == 0) boff[NB] = E;
}

// ---- LDS-binned scatter: items grouped by bucket, coalesced bursts ----
// item = (dst&127)<<24 | (etype*N + src)   [requires R*N < 2^24, guarded]
__global__ __launch_bounds__(1024)
void bucket_scatter(const int* __restrict__ dst, const int* __restrict__ src,
                    const int* __restrict__ etypes, int E, int N, int NB,
                    int* __restrict__ bcur, int* __restrict__ items) {
    __shared__ int lh[1024], lb[1024];
    int t = threadIdx.x;
    lh[t] = 0;
    __syncthreads();
    long base = (long)blockIdx.x * 8192;
    int bs[8], it[8];
    #pragma unroll
    for (int i = 0; i < 8; i++) {
        long e = base + t + 1024 * i;
        if (e < E) {
            int d = dst[e];
            int bkt = d >> 7;
            bs[i] = bkt;
            it[i] = ((d & 127) << 24) | (etypes[e] * N + src[e]);
            atomicAdd(&lh[bkt], 1);
        } else bs[i] = -1;
    }
    __syncthreads();
    for (int bb = t; bb < NB; bb += 1024) {
        int c = lh[bb];
        lb[bb] = c ? atomicAdd(&bcur[bb], c) : 0;
        lh[bb] = 0;
    }
    __syncthreads();
    #pragma unroll
    for (int i = 0; i < 8; i++) {
        if (bs[i] >= 0) {
            int pos = lb[bs[i]] + atomicAdd(&lh[bs[i]], 1);
            items[pos] = it[i];
        }
    }
}

// ---- per-bucket reduce: LDS fp32 accum over 128 dsts x 64 cols ----
// half-wave per edge: 32 lanes x 4B = full 128B proj row, LDS atomicAdd.
__global__ __launch_bounds__(256)
void bucket_reduce(const int* __restrict__ boff, const int* __restrict__ items,
                   const __bf16* __restrict__ projb, int N,
                   float* __restrict__ out) {
    __shared__ float accum[128 * 65];   // +1 row pad: mixes ds_add banks
    int b = blockIdx.x, t = threadIdx.x;
    for (int i = t; i < 128 * 65; i += 256) accum[i] = 0.f;
    __syncthreads();

    int j0 = boff[b], j1 = boff[b + 1];
    int wave = t >> 6, lane = t & 63;
    int half = lane >> 5, hl = lane & 31;
    for (int j = j0 + wave * 2 + half; j < j1; j += 8) {
        int it = items[j];
        int p = it & 0xFFFFFF;
        int dl = ((unsigned)it) >> 24;
        unsigned v = *(const unsigned*)(projb + (size_t)p * 64 + hl * 2);
        float f0 = __uint_as_float((v & 0xFFFFu) << 16);
        float f1 = __uint_as_float(v & 0xFFFF0000u);
        atomicAdd(&accum[dl * 65 + hl * 2], f0);
        atomicAdd(&accum[dl * 65 + hl * 2 + 1], f1);
    }
    __syncthreads();

    // writeout: unpermute c' = (col&15)*4 + (col>>4); coalesced fp32 stores
    int v0 = b << 7;
    int col = lane;
    int cp = (col & 15) * 4 + (col >> 4);
    for (int i = wave; i < 128; i += 4) {
        int vtx = v0 + i;
        if (vtx < N) out[(size_t)vtx * 64 + col] = accum[i * 65 + cp];
    }
}

// ---- fallback: atomic scatter (R4, known-good 433us; no ws use) ----
__global__ __launch_bounds__(NTHREADS)
void rgcn_atomic(const float* __restrict__ feat, const float* __restrict__ weight,
                 const int* __restrict__ src, const int* __restrict__ dst,
                 const int* __restrict__ etypes, int E,
                 float* __restrict__ out) {
    __shared__ __bf16 Wt[64 * 136];
    int b = blockIdx.x;
    int e0 = b * TM;
    int t = threadIdx.x;
    int wave = t >> 6, lane = t & 63;
    int q = lane >> 4, m = lane & 15;
    int wbase = e0 + wave * 16;
    int last = e0 + TM - 1; if (last > E - 1) last = E - 1;
    int rmin = etypes[e0];
    int rmax = etypes[last];
    int em = wbase + m;
    bool rowok = em < E;
    int ei = rowok ? em : E - 1;
    int my_et = rowok ? etypes[em] : -1;
    const float* arow = feat + (long)src[ei] * 128;
    bf16x8 a[4];
    #pragma unroll
    for (int ks = 0; ks < 4; ks++) {
        float4 fa = *(const float4*)(arow + ks * 32 + q * 8);
        float4 fb = *(const float4*)(arow + ks * 32 + q * 8 + 4);
        bf16x8 v;
        v[0] = (__bf16)fa.x; v[1] = (__bf16)fa.y;
        v[2] = (__bf16)fa.z; v[3] = (__bf16)fa.w;
        v[4] = (__bf16)fb.x; v[5] = (__bf16)fb.y;
        v[6] = (__bf16)fb.z; v[7] = (__bf16)fb.w;
        a[ks] = v;
    }
    f32x4 acc0 = {0.f, 0.f, 0.f, 0.f};
    f32x4 acc1 = {0.f, 0.f, 0.f, 0.f};
    f32x4 acc2 = {0.f, 0.f, 0.f, 0.f};
    f32x4 acc3 = {0.f, 0.f, 0.f, 0.f};
    for (int r = rmin; r <= rmax; ++r) {
        if (r != rmin) __syncthreads();
        const float* wg = weight + (r << 13);
        for (int p = t; p < 4096; p += NTHREADS) {
            int n = p & 63, kh = p >> 6;
            float w0 = wg[(kh * 2) * 64 + n];
            float w1 = wg[(kh * 2 + 1) * 64 + n];
            union { unsigned u; __bf16 h[2]; } pk;
            pk.h[0] = (__bf16)w0; pk.h[1] = (__bf16)w1;
            *(unsigned*)&Wt[n * 136 + kh * 2] = pk.u;
        }
        __syncthreads();
        bool on = (my_et == r);
        #pragma unroll
        for (int ks = 0; ks < 4; ks++) {
            bf16x8 af = a[ks];
            if (!on) {
                #pragma unroll
                for (int j = 0; j < 8; j++) af[j] = (__bf16)0.f;
            }
            bf16x8 b0 = *(const bf16x8*)(&Wt[(0 * 16 + m) * 136 + ks * 32 + q * 8]);
            bf16x8 b1 = *(const bf16x8*)(&Wt[(1 * 16 + m) * 136 + ks * 32 + q * 8]);
            bf16x8 b2 = *(const bf16x8*)(&Wt[(2 * 16 + m) * 136 + ks * 32 + q * 8]);
            bf16x8 b3 = *(const bf16x8*)(&Wt[(3 * 16 + m) * 136 + ks * 32 + q * 8]);
            acc0 = __builtin_amdgcn_mfma_f32_16x16x32_bf16(af, b0, acc0, 0, 0, 0);
            acc1 = __builtin_amdgcn_mfma_f32_16x16x32_bf16(af, b1, acc1, 0, 0, 0);
            acc2 = __builtin_amdgcn_mfma_f32_16x16x32_bf16(af, b2, acc2, 0, 0, 0);
            acc3 = __builtin_amdgcn_mfma_f32_16x16x32_bf16(af, b3, acc3, 0, 0, 0);
        }
    }
    #pragma unroll
    for (int reg = 0; reg < 4; reg++) {
        int er = wbase + q * 4 + reg;
        if (er < E) {
            float* orow = out + (long)dst[er] * 64;
            unsafeAtomicAdd(orow + 0 * 16 + m, acc0[reg]);
            unsafeAtomicAdd(orow + 1 * 16 + m, acc1[reg]);
            unsafeAtomicAdd(orow + 2 * 16 + m, acc2[reg]);
            unsafeAtomicAdd(orow + 3 * 16 + m, acc3[reg]);
        }
    }
}

extern "C" void kernel_launch(void* const* d_in, const int* in_sizes, int n_in,
                              void* d_out, int out_size, void* d_ws, size_t ws_size,
                              hipStream_t stream) {
    const float* feat   = (const float*)d_in[0];
    const float* weight = (const float*)d_in[1];
    const int*   src    = (const int*)d_in[2];
    const int*   dst    = (const int*)d_in[3];
    const int*   etypes = (const int*)d_in[4];
    float* out = (float*)d_out;

    int nfeat = in_sizes[0];
    int nw    = in_sizes[1];
    int E     = in_sizes[2];
    int N     = nfeat / 128;
    int R     = nw >> 13;
    int NB    = (N + 127) >> 7;      // buckets of 128 dsts

    // ws layout (256B-aligned slabs)
    size_t o = 0;
    auto take = [&](size_t bytes) { size_t r = o; o = (o + bytes + 255) & ~(size_t)255; return r; };
    size_t o_bhist = take((size_t)NB * 4);
    size_t o_boff  = take((size_t)(NB + 1) * 4);
    size_t o_bcur  = take((size_t)NB * 4);
    size_t o_items = take((size_t)E * 4);
    size_t o_wtb   = take((size_t)nw * 2);
    size_t o_featb = take((size_t)nfeat * 2);
    size_t o_projb = take((size_t)R * N * 64 * 2);
    size_t need = o;

    bool fast = (ws_size >= need) && (NB <= 1024) && ((size_t)R * N < (1u << 24));

    if (fast) {
        char* ws = (char*)d_ws;
        int* bhist = (int*)(ws + o_bhist);
        int* boff  = (int*)(ws + o_boff);
        int* bcur  = (int*)(ws + o_bcur);
        int* items = (int*)(ws + o_items);
        __bf16* wtb   = (__bf16*)(ws + o_wtb);
        __bf16* featb = (__bf16*)(ws + o_featb);
        __bf16* projb = (__bf16*)(ws + o_projb);

        int cgrid = (int)(((long)E + 8191) / 8192);

        hipMemsetAsync(bhist, 0, (size_t)NB * 4, stream);
        bucket_hist<<<cgrid, 1024, 0, stream>>>(dst, E, bhist);
        bucket_scan<<<1, 1024, 0, stream>>>(bhist, NB, E, boff, bcur);
        bucket_scatter<<<cgrid, 1024, 0, stream>>>(dst, src, etypes, E, N, NB, bcur, items);
        cvt_w_kernel<<<(nw + 255) / 256, 256, 0, stream>>>(weight, wtb, nw);
        cvt_feat_kernel<<<(nfeat / 8 + 255) / 256, 256, 0, stream>>>(feat, featb, nfeat);

        dim3 pgrid((N + 127) / 128, R);
        proj_kernel<<<pgrid, NTHREADS, 0, stream>>>(featb, wtb, N, projb);
        bucket_reduce<<<NB, 256, 0, stream>>>(boff, items, projb, N, out);
    } else {
        hipMemsetAsync(d_out, 0, (size_t)out_size * sizeof(float), stream);
        int mgrid = (E + TM - 1) / TM;
        rgcn_atomic<<<mgrid, NTHREADS, 0, stream>>>(feat, weight, src, dst, etypes, E, out);
    }
}

// Round 11
// 303.913 us; speedup vs baseline: 3.0171x; 3.0171x over previous
//
#include <hip/hip_runtime.h>
#include <hip/hip_bf16.h>

// RGCN gather-mm, etype-sorted edges.
// out[v][n] = sum_{e: dst[e]=v} sum_k feat[src[e]][k] * W[etype[e]][k][n]
//
// R11: dense projection (proj[r] = feat @ W[r], 26.2 GFLOP, zero gather)
// + two-level dst sort: bucket scatter (dst>>7, LDS-binned -> coalesced
// bursts; R9's exact scatter burned 110us on write amplification) + per-
// bucket REFINE to exact dst order (LDS counting sort, writes confined to
// the bucket's 8KB window) + R9's proven wave-per-dst gather-reduce
// (R10's per-bucket LDS-atomic reduce was latency-serialized: 688us).
// Fallback: R4 atomic kernel (433us, known-good).

#define NTHREADS 256
#define TM 64

typedef __attribute__((ext_vector_type(8))) __bf16 bf16x8;
typedef __attribute__((ext_vector_type(4))) float f32x4;

// ---- cvt: feat fp32 -> bf16 ----
__global__ void cvt_feat_kernel(const float* __restrict__ f,
                                __bf16* __restrict__ o, int n) {
    int i = (blockIdx.x * 256 + threadIdx.x) * 8;
    if (i >= n) return;
    float4 a = *(const float4*)(f + i);
    float4 b = *(const float4*)(f + i + 4);
    bf16x8 v;
    v[0] = (__bf16)a.x; v[1] = (__bf16)a.y; v[2] = (__bf16)a.z; v[3] = (__bf16)a.w;
    v[4] = (__bf16)b.x; v[5] = (__bf16)b.y; v[6] = (__bf16)b.z; v[7] = (__bf16)b.w;
    *(bf16x8*)(o + i) = v;
}

// ---- cvt: W [R][128][64] fp32 -> Wt [R][64][128] bf16 (transposed) ----
__global__ void cvt_w_kernel(const float* __restrict__ w,
                             __bf16* __restrict__ o, int total) {
    int idx = blockIdx.x * 256 + threadIdx.x;
    if (idx >= total) return;
    int r = idx >> 13;
    int rem = idx & 8191;
    int k = rem >> 6;
    int n = rem & 63;
    o[(r << 13) + (n << 7) + k] = (__bf16)w[idx];
}

// ---- dense projection: proj[r][node][c'] = (feat @ W[r]) permuted, NT ----
__global__ __launch_bounds__(NTHREADS)
void proj_kernel(const __bf16* __restrict__ featb, const __bf16* __restrict__ wtb,
                 int N, __bf16* __restrict__ projb) {
    __shared__ __bf16 Wt[64 * 136];

    int r = blockIdx.y;
    int t = threadIdx.x;
    const __bf16* wg = wtb + (r << 13);
    #pragma unroll
    for (int c = t; c < 1024; c += NTHREADS) {
        int n = c >> 4, kc = c & 15;
        *(bf16x8*)(&Wt[n * 136 + kc * 8]) = *(const bf16x8*)(wg + n * 128 + kc * 8);
    }
    __syncthreads();

    int wave = t >> 6, lane = t & 63;
    int q = lane >> 4, m = lane & 15;
    long node0 = (long)blockIdx.x * 128 + wave * 32;

    bf16x8 a[2][4];
    #pragma unroll
    for (int mt = 0; mt < 2; mt++) {
        long nd = node0 + mt * 16 + m;
        if (nd > N - 1) nd = N - 1;
        const __bf16* arow = featb + nd * 128;
        #pragma unroll
        for (int ks = 0; ks < 4; ks++)
            a[mt][ks] = *(const bf16x8*)(arow + ks * 32 + q * 8);
    }

    f32x4 acc[2][4] = {};
    #pragma unroll
    for (int ks = 0; ks < 4; ks++) {
        bf16x8 b0 = *(const bf16x8*)(&Wt[(0 * 16 + m) * 136 + ks * 32 + q * 8]);
        bf16x8 b1 = *(const bf16x8*)(&Wt[(1 * 16 + m) * 136 + ks * 32 + q * 8]);
        bf16x8 b2 = *(const bf16x8*)(&Wt[(2 * 16 + m) * 136 + ks * 32 + q * 8]);
        bf16x8 b3 = *(const bf16x8*)(&Wt[(3 * 16 + m) * 136 + ks * 32 + q * 8]);
        #pragma unroll
        for (int mt = 0; mt < 2; mt++) {
            acc[mt][0] = __builtin_amdgcn_mfma_f32_16x16x32_bf16(a[mt][ks], b0, acc[mt][0], 0, 0, 0);
            acc[mt][1] = __builtin_amdgcn_mfma_f32_16x16x32_bf16(a[mt][ks], b1, acc[mt][1], 0, 0, 0);
            acc[mt][2] = __builtin_amdgcn_mfma_f32_16x16x32_bf16(a[mt][ks], b2, acc[mt][2], 0, 0, 0);
            acc[mt][3] = __builtin_amdgcn_mfma_f32_16x16x32_bf16(a[mt][ks], b3, acc[mt][3], 0, 0, 0);
        }
    }

    // C/D: col = nt*16+m, node = mt*16+q*4+reg. Permuted c' = m*4+nt.
    #pragma unroll
    for (int mt = 0; mt < 2; mt++) {
        #pragma unroll
        for (int reg = 0; reg < 4; reg++) {
            long nd = node0 + mt * 16 + q * 4 + reg;
            if (nd < N) {
                union { unsigned long long u; __bf16 h[4]; } pk;
                pk.h[0] = (__bf16)acc[mt][0][reg];
                pk.h[1] = (__bf16)acc[mt][1][reg];
                pk.h[2] = (__bf16)acc[mt][2][reg];
                pk.h[3] = (__bf16)acc[mt][3][reg];
                __builtin_nontemporal_store(pk.u,
                    (unsigned long long*)(projb + ((size_t)r * N + nd) * 64 + m * 4));
            }
        }
    }
}

// ---- bucket histogram (bucket = dst>>7) ----
__global__ __launch_bounds__(1024)
void bucket_hist(const int* __restrict__ dst, int E, int* __restrict__ bhist) {
    __shared__ int lh[1024];
    int t = threadIdx.x;
    lh[t] = 0;
    __syncthreads();
    long base = (long)blockIdx.x * 8192;
    #pragma unroll
    for (int i = 0; i < 8; i++) {
        long e = base + t + 1024 * i;
        if (e < E) atomicAdd(&lh[dst[e] >> 7], 1);
    }
    __syncthreads();
    if (lh[t]) atomicAdd(&bhist[t], lh[t]);
}

// ---- scan buckets (NB <= 1024) -> boff (exclusive) + bcur; dofs[N]=E ----
__global__ __launch_bounds__(1024)
void bucket_scan(const int* __restrict__ bhist, int NB, int N, int E,
                 int* __restrict__ boff, int* __restrict__ bcur,
                 int* __restrict__ dofs) {
    __shared__ int sm[1024];
    int t = threadIdx.x;
    int v = (t < NB) ? bhist[t] : 0;
    sm[t] = v;
    __syncthreads();
    for (int s = 1; s < 1024; s <<= 1) {
        int add = (t >= s) ? sm[t - s] : 0;
        __syncthreads();
        sm[t] += add;
        __syncthreads();
    }
    if (t < NB) { int ex = sm[t] - v; boff[t] = ex; bcur[t] = ex; }
    if (t == 0) { boff[NB] = E; dofs[N] = E; }
}

// ---- LDS-binned scatter: items grouped by bucket, coalesced bursts ----
// item = (dst&127)<<24 | (etype*N + src)   [R*N < 2^24 guarded]
__global__ __launch_bounds__(1024)
void bucket_scatter(const int* __restrict__ dst, const int* __restrict__ src,
                    const int* __restrict__ etypes, int E, int N, int NB,
                    int* __restrict__ bcur, int* __restrict__ items) {
    __shared__ int lh[1024], lb[1024];
    int t = threadIdx.x;
    lh[t] = 0;
    __syncthreads();
    long base = (long)blockIdx.x * 8192;
    int bs[8], it[8];
    #pragma unroll
    for (int i = 0; i < 8; i++) {
        long e = base + t + 1024 * i;
        if (e < E) {
            int d = dst[e];
            int bkt = d >> 7;
            bs[i] = bkt;
            it[i] = ((d & 127) << 24) | (etypes[e] * N + src[e]);
            atomicAdd(&lh[bkt], 1);
        } else bs[i] = -1;
    }
    __syncthreads();
    for (int bb = t; bb < NB; bb += 1024) {
        int c = lh[bb];
        lb[bb] = c ? atomicAdd(&bcur[bb], c) : 0;
        lh[bb] = 0;
    }
    __syncthreads();
    #pragma unroll
    for (int i = 0; i < 8; i++) {
        if (bs[i] >= 0) {
            int pos = lb[bs[i]] + atomicAdd(&lh[bs[i]], 1);
            items[pos] = it[i];
        }
    }
}

// ---- refine: exact-dst order within each bucket (LDS counting sort) ----
// Emits pidx (dst-sorted proj-row indices) + per-dst offsets dofs[v].
// All global writes confined to this bucket's windows (L2-absorbed).
__global__ __launch_bounds__(256)
void refine_kernel(const int* __restrict__ boff, const int* __restrict__ items,
                   int N, int* __restrict__ pidx, int* __restrict__ dofs) {
    __shared__ int h[128], sc[128], cur[128];
    int b = blockIdx.x, t = threadIdx.x;
    int j0 = boff[b], j1 = boff[b + 1];
    if (t < 128) h[t] = 0;
    __syncthreads();
    for (int j = j0 + t; j < j1; j += 256)
        atomicAdd(&h[((unsigned)items[j]) >> 24], 1);
    __syncthreads();
    if (t < 128) sc[t] = h[t];
    __syncthreads();
    for (int s = 1; s < 128; s <<= 1) {            // inclusive scan
        int add = (t >= s && t < 128) ? sc[t - s] : 0;
        __syncthreads();
        if (t < 128) sc[t] += add;
        __syncthreads();
    }
    if (t < 128) {
        int ex = sc[t] - h[t];                     // exclusive
        cur[t] = ex;
        int v = (b << 7) + t;
        if (v < N) dofs[v] = j0 + ex;
    }
    __syncthreads();
    for (int j = j0 + t; j < j1; j += 256) {
        int it = items[j];
        int dl = ((unsigned)it) >> 24;
        int pos = j0 + atomicAdd(&cur[dl], 1);
        pidx[pos] = it & 0xFFFFFF;
    }
}

// ---- wave-per-dst gather-reduce (R9, proven) over permuted proj rows ----
__global__ __launch_bounds__(256)
void reduce_kernel(const int* __restrict__ dofs, const int* __restrict__ pidx,
                   const __bf16* __restrict__ projb, int N, float* __restrict__ out) {
    int gid = blockIdx.x * 256 + threadIdx.x;
    int w = gid >> 6, lane = gid & 63;
    int nw = (gridDim.x * 256) >> 6;
    int sub = lane >> 3, c8 = lane & 7;
    for (int v = w; v < N; v += nw) {
        int j0 = dofs[v], j1 = dofs[v + 1];
        float acc[8] = {0.f, 0.f, 0.f, 0.f, 0.f, 0.f, 0.f, 0.f};
        for (int j = j0 + sub; j < j1; j += 8) {
            int p = pidx[j];
            bf16x8 val = *(const bf16x8*)(projb + (size_t)p * 64 + c8 * 8);
            #pragma unroll
            for (int i = 0; i < 8; i++) acc[i] += (float)val[i];
        }
        #pragma unroll
        for (int mask = 8; mask <= 32; mask <<= 1) {
            #pragma unroll
            for (int i = 0; i < 8; i++) acc[i] += __shfl_xor(acc[i], mask, 64);
        }
        if (sub == 0) {
            float* orow = out + (size_t)v * 64;
            #pragma unroll
            for (int i = 0; i < 8; i++) {
                int cp = c8 * 8 + i;
                orow[(cp & 3) * 16 + (cp >> 2)] = acc[i];
            }
        }
    }
}

// ---- fallback: atomic scatter (R4, known-good 433us; no ws use) ----
__global__ __launch_bounds__(NTHREADS)
void rgcn_atomic(const float* __restrict__ feat, const float* __restrict__ weight,
                 const int* __restrict__ src, const int* __restrict__ dst,
                 const int* __restrict__ etypes, int E,
                 float* __restrict__ out) {
    __shared__ __bf16 Wt[64 * 136];
    int b = blockIdx.x;
    int e0 = b * TM;
    int t = threadIdx.x;
    int wave = t >> 6, lane = t & 63;
    int q = lane >> 4, m = lane & 15;
    int wbase = e0 + wave * 16;
    int last = e0 + TM - 1; if (last > E - 1) last = E - 1;
    int rmin = etypes[e0];
    int rmax = etypes[last];
    int em = wbase + m;
    bool rowok = em < E;
    int ei = rowok ? em : E - 1;
    int my_et = rowok ? etypes[em] : -1;
    const float* arow = feat + (long)src[ei] * 128;
    bf16x8 a[4];
    #pragma unroll
    for (int ks = 0; ks < 4; ks++) {
        float4 fa = *(const float4*)(arow + ks * 32 + q * 8);
        float4 fb = *(const float4*)(arow + ks * 32 + q * 8 + 4);
        bf16x8 v;
        v[0] = (__bf16)fa.x; v[1] = (__bf16)fa.y;
        v[2] = (__bf16)fa.z; v[3] = (__bf16)fa.w;
        v[4] = (__bf16)fb.x; v[5] = (__bf16)fb.y;
        v[6] = (__bf16)fb.z; v[7] = (__bf16)fb.w;
        a[ks] = v;
    }
    f32x4 acc0 = {0.f, 0.f, 0.f, 0.f};
    f32x4 acc1 = {0.f, 0.f, 0.f, 0.f};
    f32x4 acc2 = {0.f, 0.f, 0.f, 0.f};
    f32x4 acc3 = {0.f, 0.f, 0.f, 0.f};
    for (int r = rmin; r <= rmax; ++r) {
        if (r != rmin) __syncthreads();
        const float* wg = weight + (r << 13);
        for (int p = t; p < 4096; p += NTHREADS) {
            int n = p & 63, kh = p >> 6;
            float w0 = wg[(kh * 2) * 64 + n];
            float w1 = wg[(kh * 2 + 1) * 64 + n];
            union { unsigned u; __bf16 h[2]; } pk;
            pk.h[0] = (__bf16)w0; pk.h[1] = (__bf16)w1;
            *(unsigned*)&Wt[n * 136 + kh * 2] = pk.u;
        }
        __syncthreads();
        bool on = (my_et == r);
        #pragma unroll
        for (int ks = 0; ks < 4; ks++) {
            bf16x8 af = a[ks];
            if (!on) {
                #pragma unroll
                for (int j = 0; j < 8; j++) af[j] = (__bf16)0.f;
            }
            bf16x8 b0 = *(const bf16x8*)(&Wt[(0 * 16 + m) * 136 + ks * 32 + q * 8]);
            bf16x8 b1 = *(const bf16x8*)(&Wt[(1 * 16 + m) * 136 + ks * 32 + q * 8]);
            bf16x8 b2 = *(const bf16x8*)(&Wt[(2 * 16 + m) * 136 + ks * 32 + q * 8]);
            bf16x8 b3 = *(const bf16x8*)(&Wt[(3 * 16 + m) * 136 + ks * 32 + q * 8]);
            acc0 = __builtin_amdgcn_mfma_f32_16x16x32_bf16(af, b0, acc0, 0, 0, 0);
            acc1 = __builtin_amdgcn_mfma_f32_16x16x32_bf16(af, b1, acc1, 0, 0, 0);
            acc2 = __builtin_amdgcn_mfma_f32_16x16x32_bf16(af, b2, acc2, 0, 0, 0);
            acc3 = __builtin_amdgcn_mfma_f32_16x16x32_bf16(af, b3, acc3, 0, 0, 0);
        }
    }
    #pragma unroll
    for (int reg = 0; reg < 4; reg++) {
        int er = wbase + q * 4 + reg;
        if (er < E) {
            float* orow = out + (long)dst[er] * 64;
            unsafeAtomicAdd(orow + 0 * 16 + m, acc0[reg]);
            unsafeAtomicAdd(orow + 1 * 16 + m, acc1[reg]);
            unsafeAtomicAdd(orow + 2 * 16 + m, acc2[reg]);
            unsafeAtomicAdd(orow + 3 * 16 + m, acc3[reg]);
        }
    }
}

extern "C" void kernel_launch(void* const* d_in, const int* in_sizes, int n_in,
                              void* d_out, int out_size, void* d_ws, size_t ws_size,
                              hipStream_t stream) {
    const float* feat   = (const float*)d_in[0];
    const float* weight = (const float*)d_in[1];
    const int*   src    = (const int*)d_in[2];
    const int*   dst    = (const int*)d_in[3];
    const int*   etypes = (const int*)d_in[4];
    float* out = (float*)d_out;

    int nfeat = in_sizes[0];
    int nw    = in_sizes[1];
    int E     = in_sizes[2];
    int N     = nfeat / 128;
    int R     = nw >> 13;
    int NB    = (N + 127) >> 7;      // buckets of 128 dsts

    // ws layout (256B-aligned slabs)
    size_t o = 0;
    auto take = [&](size_t bytes) { size_t r = o; o = (o + bytes + 255) & ~(size_t)255; return r; };
    size_t o_bhist = take((size_t)NB * 4);
    size_t o_boff  = take((size_t)(NB + 1) * 4);
    size_t o_bcur  = take((size_t)NB * 4);
    size_t o_dofs  = take((size_t)(N + 1) * 4);
    size_t o_items = take((size_t)E * 4);
    size_t o_pidx  = take((size_t)E * 4);
    size_t o_wtb   = take((size_t)nw * 2);
    size_t o_featb = take((size_t)nfeat * 2);
    size_t o_projb = take((size_t)R * N * 64 * 2);
    size_t need = o;

    bool fast = (ws_size >= need) && (NB <= 1024) && ((size_t)R * N < (1u << 24));

    if (fast) {
        char* ws = (char*)d_ws;
        int* bhist = (int*)(ws + o_bhist);
        int* boff  = (int*)(ws + o_boff);
        int* bcur  = (int*)(ws + o_bcur);
        int* dofs  = (int*)(ws + o_dofs);
        int* items = (int*)(ws + o_items);
        int* pidx  = (int*)(ws + o_pidx);
        __bf16* wtb   = (__bf16*)(ws + o_wtb);
        __bf16* featb = (__bf16*)(ws + o_featb);
        __bf16* projb = (__bf16*)(ws + o_projb);

        int cgrid = (int)(((long)E + 8191) / 8192);

        hipMemsetAsync(bhist, 0, (size_t)NB * 4, stream);
        bucket_hist<<<cgrid, 1024, 0, stream>>>(dst, E, bhist);
        bucket_scan<<<1, 1024, 0, stream>>>(bhist, NB, N, E, boff, bcur, dofs);
        bucket_scatter<<<cgrid, 1024, 0, stream>>>(dst, src, etypes, E, N, NB, bcur, items);
        refine_kernel<<<NB, 256, 0, stream>>>(boff, items, N, pidx, dofs);
        cvt_w_kernel<<<(nw + 255) / 256, 256, 0, stream>>>(weight, wtb, nw);
        cvt_feat_kernel<<<(nfeat / 8 + 255) / 256, 256, 0, stream>>>(feat, featb, nfeat);

        dim3 pgrid((N + 127) / 128, R);
        proj_kernel<<<pgrid, NTHREADS, 0, stream>>>(featb, wtb, N, projb);
        reduce_kernel<<<2048, 256, 0, stream>>>(dofs, pidx, projb, N, out);
    } else {
        hipMemsetAsync(d_out, 0, (size_t)out_size * sizeof(float), stream);
        int mgrid = (E + TM - 1) / TM;
        rgcn_atomic<<<mgrid, NTHREADS, 0, stream>>>(feat, weight, src, dst, etypes, E, out);
    }
}